// Round 8
// baseline (139.793 us; speedup 1.0000x reference)
//
#include <hip/hip_runtime.h>

#define CDIM 64
#define TDIM 24
#define NDIM 512
#define NBT  192   // B*T = 8*24

typedef float    float4v __attribute__((ext_vector_type(4)));
typedef _Float16 half8v  __attribute__((ext_vector_type(8)));
typedef _Float16 half4v  __attribute__((ext_vector_type(4)));
typedef _Float16 half2v  __attribute__((ext_vector_type(2)));

// ---------------------------------------------------------------------------
// Workspace layout (bytes):
//   VT_g   : _Float16 [NBT][64][512]   0          (12582912 B)
//   s_src  : float    [NBT][2][512]    12582912   (786432 B)   (exp2 domain)
//   s_dst  : float    [NBT][2][512]    13369344   (786432 B)   (exp2 domain)
//   maskb  : u8       [512][512]       14155776   (262144 B)   {0x00,0xFF}
// ---------------------------------------------------------------------------

__device__ __forceinline__ float exp2_fast(float x) {
#if __has_builtin(__builtin_amdgcn_exp2f)
  return __builtin_amdgcn_exp2f(x);
#else
  return __expf(x * 0.69314718f);
#endif
}

__device__ __forceinline__ half2v pk2(float a, float b) {
  return __builtin_bit_cast(half2v, __builtin_amdgcn_cvt_pkrtz(a, b));
}

// ======== kernel 1: V = X @ Wv^T (f16 MFMA) + score cols + mask pack ========
// 1D grid, 832 blocks:
//   blocks 0..767  : compute; qn = bx & 3 (node quarter), bt = bx >> 2
//   blocks 768..831: gso -> u8-mask pack (pure BW, overlaps compute blocks)
struct SmemK1 {
  union {
    _Float16 xt[128][72];    // X tile [node][c], 144 B rows (16B aligned, b128-readable)
    _Float16 vtb[64][136];   // V^T bounce [c][node]
  } big;                     // 18432 B
  _Float16 wv[64][72];       // Wv [d][k]             9216 B
  _Float16 wext[16][72];     // rows 0..3 = log2e * (a_h^T W_h), rest 0   2304 B
};                            // 29952 B -> 4 blocks/CU

__launch_bounds__(256, 4)
__global__ void k1_v(const float* __restrict__ x,  const float* __restrict__ Wv,
                     const float* __restrict__ Wq, const float* __restrict__ Wk,
                     const float* __restrict__ a_src, const float* __restrict__ a_dst,
                     const int* __restrict__ gso,
                     _Float16* __restrict__ VT_g,
                     float* __restrict__ s_src_g, float* __restrict__ s_dst_g,
                     unsigned char* __restrict__ maskb) {
  const int t  = threadIdx.x;
  const int bx = blockIdx.x;

  if (bx >= 768) {   // ---- mask-pack blocks: 16 ints -> 16 mask bytes each ----
    int g = (bx - 768) * 256 + t;            // 0..16383
    const int4* gp = (const int4*)gso + (size_t)g * 4;
    unsigned w[4];
#pragma unroll
    for (int k = 0; k < 4; ++k) {
      int4 v = gp[k];
      w[k] = (v.x ? 0x000000FFu : 0u) | (v.y ? 0x0000FF00u : 0u) |
             (v.z ? 0x00FF0000u : 0u) | (v.w ? 0xFF000000u : 0u);
    }
    uint4 o; o.x = w[0]; o.y = w[1]; o.z = w[2]; o.w = w[3];
    ((uint4*)maskb)[g] = o;
    return;
  }

  __shared__ SmemK1 sm;
  const int qn = bx & 3;
  const int bt = bx >> 2;
  const int b  = bt / TDIM, tt = bt % TDIM;
  const int n0 = qn * 128;

  // stage Wv -> f16 LDS (float4 + pkrtz, half4 stores)
#pragma unroll
  for (int it = 0; it < 4; ++it) {
    int idx = it * 256 + t;           // 1024 float4 chunks
    int d = idx >> 4, k4 = (idx & 15) * 4;
    float4 v = ((const float4*)Wv)[idx];
    half2v p0 = pk2(v.x, v.y), p1 = pk2(v.z, v.w);
    half4v h4; h4[0] = p0[0]; h4[1] = p0[1]; h4[2] = p1[0]; h4[3] = p1[1];
    *(half4v*)&sm.wv[d][k4] = h4;
  }
  // wext: zero rows 4..15; rows 0..3 = log2e * (a_h^T W_h)  (exp2 domain)
  for (int z = t; z < 12 * 72; z += 256) ((_Float16*)sm.wext[4])[z] = (_Float16)0.f;
  {
    // 256 threads = 4 rows x 64 cols, one accumulator each, coalesced loads
    int r = t >> 6, c = t & 63;
    const float* av = (r & 2) ? a_dst : a_src;
    const float* W  = (r & 2) ? Wk : Wq;
    int off = (r & 1) * 32;
    float s = 0.f;
#pragma unroll
    for (int d = 0; d < 32; ++d)
      s += av[off + d] * W[(off + d) * 64 + c];
    sm.wext[r][c] = (_Float16)(s * 1.44269504f);
  }
  // stage X tile (channel pairs -> half2)
  for (int it = 0; it < 16; ++it) {
    int idx = it * 256 + t;
    int cp = idx >> 7, n = idx & 127;
    int c0 = cp * 2;
    const float* base = x + ((size_t)(b * CDIM + c0) * TDIM + tt) * NDIM + n0 + n;
    *(half2v*)&sm.big.xt[n][c0] = pk2(base[0], base[(size_t)TDIM * NDIM]);
  }
  __syncthreads();

  const int lane = t & 63, w = t >> 6;
  const int m = lane & 15, quad = lane >> 4;
  const int mbase = w * 32;   // 32 nodes per wave

  float4v acc[2][5];
#pragma unroll
  for (int mt = 0; mt < 2; ++mt)
#pragma unroll
    for (int nt = 0; nt < 5; ++nt)
#pragma unroll
      for (int r = 0; r < 4; ++r) acc[mt][nt][r] = 0.f;

#pragma unroll
  for (int ks = 0; ks < 2; ++ks) {
    half8v af[2], bf[5];
#pragma unroll
    for (int mt = 0; mt < 2; ++mt)
      af[mt] = *(const half8v*)&sm.big.xt[mbase + mt * 16 + m][ks * 32 + quad * 8];
#pragma unroll
    for (int nt = 0; nt < 4; ++nt)
      bf[nt] = *(const half8v*)&sm.wv[nt * 16 + m][ks * 32 + quad * 8];
    bf[4] = *(const half8v*)&sm.wext[m][ks * 32 + quad * 8];
#pragma unroll
    for (int mt = 0; mt < 2; ++mt)
#pragma unroll
      for (int nt = 0; nt < 5; ++nt)
        acc[mt][nt] = __builtin_amdgcn_mfma_f32_16x16x32_f16(af[mt], bf[nt], acc[mt][nt], 0, 0, 0);
  }

  // scatter score columns (col 0/1 = ssrc h0/h1, col 2/3 = sdst h0/h1)
  if (m < 4) {
    float* basep = (m < 2 ? s_src_g : s_dst_g) + (size_t)(bt * 2 + (m & 1)) * NDIM;
#pragma unroll
    for (int mt = 0; mt < 2; ++mt)
#pragma unroll
      for (int r = 0; r < 4; ++r)
        basep[n0 + mbase + mt * 16 + quad * 4 + r] = acc[mt][4][r];
  }
  __syncthreads();   // xt fully consumed before overlay

  // V^T bounce into LDS (pack node pairs)
#pragma unroll
  for (int mt = 0; mt < 2; ++mt)
#pragma unroll
    for (int nt = 0; nt < 4; ++nt)
#pragma unroll
      for (int r = 0; r < 4; r += 2) {
        int nl = mbase + mt * 16 + quad * 4 + r;
        int c  = nt * 16 + m;
        *(half2v*)&sm.big.vtb[c][nl] = pk2(acc[mt][nt][r], acc[mt][nt][r + 1]);
      }
  __syncthreads();

  // coalesced V^T -> global (64 rows x 64 dwords)
  const unsigned* vdw = (const unsigned*)sm.big.vtb;   // row stride 68 dwords
  unsigned* outdw = (unsigned*)VT_g;
  for (int it = 0; it < 16; ++it) {
    int idx = it * 256 + t;
    int c = idx >> 6, jd = idx & 63;
    outdw[(size_t)(bt * 64 + c) * 256 + qn * 64 + jd] = vdw[c * 68 + jd];
  }
}

// ======== kernel 2: masked softmax(P) @ V + LayerNorm + transpose ===========
// grid (8, NBT): blockIdx.x = i-tile (64 rows), blockIdx.y = bt
// e_ij = exp(lrelu(s_i+d_j)) = max(E_i*F_j, Ep_i*Fp_j)  (exp monotone).
// V-fragments and mask bytes load DIRECTLY from global (VT_g layout already
// matches the B-fragment order; L2-resident, no LDS round-trip, no barriers
// in the main loop).
struct SmemK2 {
  float otile[64][66];     // 16896 B
  float rsum[4][64];       // 1024
  float rsq[4][64];        // 1024
  float mu[64], rs[64];    // 512
  _Float16 sF16[2][512];   // 2048  F_j  = 2^{d'_j}   (f16)
  _Float16 sP16[2][512];   // 2048  Fp_j = 2^{0.2 d'_j} (f16)
};                          // 23552 B -> up to 6 blocks/CU

__launch_bounds__(256, 4)
__global__ void k2_attn(const _Float16* __restrict__ VT_g,
                        const float* __restrict__ s_src_g, const float* __restrict__ s_dst_g,
                        const unsigned char* __restrict__ maskb,
                        const float* __restrict__ gamma, const float* __restrict__ beta,
                        float* __restrict__ out) {
  __shared__ SmemK2 sm;
  const int t     = threadIdx.x;
  const int itile = blockIdx.x;
  const int bt    = blockIdx.y;
  const int i0    = itile * 64;
  const int b     = bt / TDIM, tt = bt % TDIM;
  const int lane  = t & 63, w = t >> 6;
  const int h = w >> 1, ihalf = w & 1;
  const int m = lane & 15, quad = lane >> 4;

  // stage F/Fp as f16 (1024 exp2 pairs per block)
  for (int it = 0; it < 4; ++it) {
    int idx = it * 256 + t;
    float d = s_dst_g[(size_t)bt * 2 * NDIM + idx];
    ((_Float16*)sm.sF16)[idx] = (_Float16)exp2_fast(d);
    ((_Float16*)sm.sP16)[idx] = (_Float16)exp2_fast(0.2f * d);
  }
  // per-row source factors as f16 splats (bias -6 keeps products f16-normal)
  half8v E8[2], Q8[2];
#pragma unroll
  for (int mt = 0; mt < 2; ++mt) {
    float sv = s_src_g[(size_t)(bt * 2 + h) * NDIM + i0 + ihalf * 32 + mt * 16 + m];
    _Float16 ev = (_Float16)exp2_fast(sv - 6.f);
    _Float16 qv = (_Float16)exp2_fast(0.2f * sv - 6.f);
#pragma unroll
    for (int jj = 0; jj < 8; ++jj) { E8[mt][jj] = ev; Q8[mt][jj] = qv; }
  }

  float4v acc[2][2], accs[2];
#pragma unroll
  for (int mt = 0; mt < 2; ++mt) {
#pragma unroll
    for (int r = 0; r < 4; ++r) { acc[mt][0][r] = 0.f; acc[mt][1][r] = 0.f; accs[mt][r] = 0.f; }
  }
  const half8v bones = {(_Float16)1.f, (_Float16)1.f, (_Float16)1.f, (_Float16)1.f,
                        (_Float16)1.f, (_Float16)1.f, (_Float16)1.f, (_Float16)1.f};

  // per-lane global base pointers (constant over the loop)
  const _Float16* vrow = VT_g + ((size_t)bt * 64 + h * 32 + m) * NDIM;
  const unsigned char* mrow0 = maskb + (size_t)(i0 + ihalf * 32 + m) * NDIM;
  const unsigned char* mrow1 = mrow0 + 16 * NDIM;

  __syncthreads();   // F/P staged

  for (int js = 0; js < 4; ++js) {
#pragma unroll
    for (int ksl = 0; ksl < 4; ++ksl) {
      int jo = js * 128 + ksl * 32 + quad * 8;   // absolute j for this lane's 8
      half8v b0 = *(const half8v*)(vrow + jo);
      half8v b1 = *(const half8v*)(vrow + 16 * NDIM + jo);
      uint2 mv0 = *(const uint2*)(mrow0 + jo);
      uint2 mv1 = *(const uint2*)(mrow1 + jo);
      half8v F8 = *(const half8v*)&sm.sF16[h][jo];
      half8v P8 = *(const half8v*)&sm.sP16[h][jo];
#pragma unroll
      for (int mt = 0; mt < 2; ++mt) {
        uint2 mv = mt ? mv1 : mv0;
        half8v e8 = __builtin_elementwise_max(E8[mt] * F8, Q8[mt] * P8);  // pk_mul/pk_max
        uint4 eu = __builtin_bit_cast(uint4, e8);
        eu.x &= __builtin_amdgcn_perm(0u, mv.x, 0x01010000u);
        eu.y &= __builtin_amdgcn_perm(0u, mv.x, 0x03030202u);
        eu.z &= __builtin_amdgcn_perm(0u, mv.y, 0x01010000u);
        eu.w &= __builtin_amdgcn_perm(0u, mv.y, 0x03030202u);
        half8v af = __builtin_bit_cast(half8v, eu);
        acc[mt][0] = __builtin_amdgcn_mfma_f32_16x16x32_f16(af, b0,    acc[mt][0], 0, 0, 0);
        acc[mt][1] = __builtin_amdgcn_mfma_f32_16x16x32_f16(af, b1,    acc[mt][1], 0, 0, 0);
        accs[mt]   = __builtin_amdgcn_mfma_f32_16x16x32_f16(af, bones, accs[mt],   0, 0, 0);
      }
    }
  }

  // normalize by row sums (same C-layout row as acc -> no shuffle needed)
#pragma unroll
  for (int mt = 0; mt < 2; ++mt)
#pragma unroll
    for (int r = 0; r < 4; ++r) {
      float sc = __builtin_amdgcn_rcpf(accs[mt][r]);
      int i_loc = ihalf * 32 + mt * 16 + quad * 4 + r;
#pragma unroll
      for (int nt = 0; nt < 2; ++nt)
        sm.otile[i_loc][h * 32 + nt * 16 + m] = acc[mt][nt][r] * sc;
    }
  __syncthreads();

  // LayerNorm over C=64 per row
  {
    int i = t & 63, cg = t >> 6;
    float s1 = 0.f, s2 = 0.f;
#pragma unroll
    for (int cc = 0; cc < 16; ++cc) {
      float v = sm.otile[i][cg * 16 + cc];
      s1 += v; s2 += v * v;
    }
    sm.rsum[cg][i] = s1;
    sm.rsq[cg][i]  = s2;
  }
  __syncthreads();
  if (t < 64) {
    int i = t;
    float s1 = 0.f, s2 = 0.f;
#pragma unroll
    for (int cg = 0; cg < 4; ++cg) { s1 += sm.rsum[cg][i]; s2 += sm.rsq[cg][i]; }
    float mu  = s1 * (1.f / 64.f);
    float var = s2 * (1.f / 64.f) - mu * mu;
    sm.mu[i] = mu;
    sm.rs[i] = rsqrtf(var + 1e-5f);
  }
  __syncthreads();
  {
    int i = t & 63, cg = t >> 6;
    float mu = sm.mu[i], rs = sm.rs[i];
    int n = i0 + i;
#pragma unroll
    for (int cc = 0; cc < 16; ++cc) {
      int c = cg * 16 + cc;
      float v = (sm.otile[i][c] - mu) * rs * gamma[c] + beta[c];
      out[((size_t)(b * CDIM + c) * TDIM + tt) * NDIM + n] = v;
    }
  }
}

// ---------------------------------------------------------------------------
extern "C" void kernel_launch(void* const* d_in, const int* in_sizes, int n_in,
                              void* d_out, int out_size, void* d_ws, size_t ws_size,
                              hipStream_t stream) {
  const float* x     = (const float*)d_in[0];
  const int*   gso   = (const int*)d_in[1];
  const float* Wq    = (const float*)d_in[2];
  const float* Wk    = (const float*)d_in[3];
  const float* Wv    = (const float*)d_in[4];
  const float* a_src = (const float*)d_in[5];
  const float* a_dst = (const float*)d_in[6];
  const float* gamma = (const float*)d_in[7];
  const float* beta  = (const float*)d_in[8];
  float* out = (float*)d_out;

  char* ws = (char*)d_ws;
  _Float16* VT_g  = (_Float16*)ws;
  float*    s_src = (float*)(ws + 12582912);
  float*    s_dst = (float*)(ws + 13369344);
  unsigned char* maskb = (unsigned char*)(ws + 14155776);

  k1_v<<<832, 256, 0, stream>>>(x, Wv, Wq, Wk, a_src, a_dst, gso,
                                VT_g, s_src, s_dst, maskb);
  k2_attn<<<dim3(8, NBT), 256, 0, stream>>>(VT_g, s_src, s_dst, maskb, gamma, beta, out);
}

// Round 9
// 133.188 us; speedup vs baseline: 1.0496x; 1.0496x over previous
//
#include <hip/hip_runtime.h>

#define CDIM 64
#define TDIM 24
#define NDIM 512
#define NBT  192   // B*T = 8*24

typedef float    float4v __attribute__((ext_vector_type(4)));
typedef _Float16 half8v  __attribute__((ext_vector_type(8)));
typedef _Float16 half4v  __attribute__((ext_vector_type(4)));
typedef _Float16 half2v  __attribute__((ext_vector_type(2)));

// ---------------------------------------------------------------------------
// Workspace layout (bytes):
//   VT_g   : _Float16 [NBT][64][512]   0          (12582912 B)
//   s_src  : float    [NBT][2][512]    12582912   (786432 B)   (exp2 domain)
//   s_dst  : float    [NBT][2][512]    13369344   (786432 B)   (exp2 domain)
//   maskb  : u8       [512][512]       14155776   (262144 B)   {0x00,0xFF}
// XCD note: both kernels use 1D grids with bt = bx % NBT, so all blocks
// sharing a bt land on XCD bt%8 (round-robin dispatch heuristic): VT[bt] is
// produced and consumed in the same XCD's L2.
// ---------------------------------------------------------------------------

__device__ __forceinline__ float exp2_fast(float x) {
#if __has_builtin(__builtin_amdgcn_exp2f)
  return __builtin_amdgcn_exp2f(x);
#else
  return __expf(x * 0.69314718f);
#endif
}

__device__ __forceinline__ half2v pk2(float a, float b) {
  return __builtin_bit_cast(half2v, __builtin_amdgcn_cvt_pkrtz(a, b));
}

// ======== kernel 1: V = X @ Wv^T (f16 MFMA) + score cols + mask pack ========
// 1D grid, 832 blocks:
//   blocks 0..767  : compute; bt = bx % NBT (XCD-aligned), qn = bx / NBT
//   blocks 768..831: gso -> u8-mask pack (pure BW, overlaps compute blocks)
struct SmemK1 {
  union {
    _Float16 xt[128][72];    // X tile [node][c], 144 B rows (16B aligned, b128-readable)
    _Float16 vtb[64][136];   // V^T bounce [c][node]
  } big;                     // 18432 B
  _Float16 wv[64][72];       // Wv [d][k]             9216 B
  _Float16 wext[16][72];     // rows 0..3 = log2e * (a_h^T W_h), rest 0   2304 B
};                            // 29952 B -> 4 blocks/CU

__launch_bounds__(256, 4)
__global__ void k1_v(const float* __restrict__ x,  const float* __restrict__ Wv,
                     const float* __restrict__ Wq, const float* __restrict__ Wk,
                     const float* __restrict__ a_src, const float* __restrict__ a_dst,
                     const int* __restrict__ gso,
                     _Float16* __restrict__ VT_g,
                     float* __restrict__ s_src_g, float* __restrict__ s_dst_g,
                     unsigned char* __restrict__ maskb) {
  const int t  = threadIdx.x;
  const int bx = blockIdx.x;

  if (bx >= 768) {   // ---- mask-pack blocks: 16 ints -> 16 mask bytes each ----
    int g = (bx - 768) * 256 + t;            // 0..16383
    const int4* gp = (const int4*)gso + (size_t)g * 4;
    unsigned w[4];
#pragma unroll
    for (int k = 0; k < 4; ++k) {
      int4 v = gp[k];
      w[k] = (v.x ? 0x000000FFu : 0u) | (v.y ? 0x0000FF00u : 0u) |
             (v.z ? 0x00FF0000u : 0u) | (v.w ? 0xFF000000u : 0u);
    }
    uint4 o; o.x = w[0]; o.y = w[1]; o.z = w[2]; o.w = w[3];
    ((uint4*)maskb)[g] = o;
    return;
  }

  __shared__ SmemK1 sm;
  const int bt = bx % NBT;       // XCD = bt % 8
  const int qn = bx / NBT;
  const int b  = bt / TDIM, tt = bt % TDIM;
  const int n0 = qn * 128;

  // stage Wv -> f16 LDS (float4 + pkrtz, half4 stores)
#pragma unroll
  for (int it = 0; it < 4; ++it) {
    int idx = it * 256 + t;           // 1024 float4 chunks
    int d = idx >> 4, k4 = (idx & 15) * 4;
    float4 v = ((const float4*)Wv)[idx];
    half2v p0 = pk2(v.x, v.y), p1 = pk2(v.z, v.w);
    half4v h4; h4[0] = p0[0]; h4[1] = p0[1]; h4[2] = p1[0]; h4[3] = p1[1];
    *(half4v*)&sm.wv[d][k4] = h4;
  }
  // wext: zero rows 4..15; rows 0..3 = log2e * (a_h^T W_h)  (exp2 domain)
  for (int z = t; z < 12 * 72; z += 256) ((_Float16*)sm.wext[4])[z] = (_Float16)0.f;
  {
    // 256 threads = 4 rows x 64 cols, one accumulator each, coalesced loads
    int r = t >> 6, c = t & 63;
    const float* av = (r & 2) ? a_dst : a_src;
    const float* W  = (r & 2) ? Wk : Wq;
    int off = (r & 1) * 32;
    float s = 0.f;
#pragma unroll
    for (int d = 0; d < 32; ++d)
      s += av[off + d] * W[(off + d) * 64 + c];
    sm.wext[r][c] = (_Float16)(s * 1.44269504f);
  }
  // stage X tile (channel pairs -> half2)
  for (int it = 0; it < 16; ++it) {
    int idx = it * 256 + t;
    int cp = idx >> 7, n = idx & 127;
    int c0 = cp * 2;
    const float* base = x + ((size_t)(b * CDIM + c0) * TDIM + tt) * NDIM + n0 + n;
    *(half2v*)&sm.big.xt[n][c0] = pk2(base[0], base[(size_t)TDIM * NDIM]);
  }
  __syncthreads();

  const int lane = t & 63, w = t >> 6;
  const int m = lane & 15, quad = lane >> 4;
  const int mbase = w * 32;   // 32 nodes per wave

  float4v acc[2][5];
#pragma unroll
  for (int mt = 0; mt < 2; ++mt)
#pragma unroll
    for (int nt = 0; nt < 5; ++nt)
#pragma unroll
      for (int r = 0; r < 4; ++r) acc[mt][nt][r] = 0.f;

#pragma unroll
  for (int ks = 0; ks < 2; ++ks) {
    half8v af[2], bf[5];
#pragma unroll
    for (int mt = 0; mt < 2; ++mt)
      af[mt] = *(const half8v*)&sm.big.xt[mbase + mt * 16 + m][ks * 32 + quad * 8];
#pragma unroll
    for (int nt = 0; nt < 4; ++nt)
      bf[nt] = *(const half8v*)&sm.wv[nt * 16 + m][ks * 32 + quad * 8];
    bf[4] = *(const half8v*)&sm.wext[m][ks * 32 + quad * 8];
#pragma unroll
    for (int mt = 0; mt < 2; ++mt)
#pragma unroll
      for (int nt = 0; nt < 5; ++nt)
        acc[mt][nt] = __builtin_amdgcn_mfma_f32_16x16x32_f16(af[mt], bf[nt], acc[mt][nt], 0, 0, 0);
  }

  // scatter score columns (col 0/1 = ssrc h0/h1, col 2/3 = sdst h0/h1)
  if (m < 4) {
    float* basep = (m < 2 ? s_src_g : s_dst_g) + (size_t)(bt * 2 + (m & 1)) * NDIM;
#pragma unroll
    for (int mt = 0; mt < 2; ++mt)
#pragma unroll
      for (int r = 0; r < 4; ++r)
        basep[n0 + mbase + mt * 16 + quad * 4 + r] = acc[mt][4][r];
  }
  __syncthreads();   // xt fully consumed before overlay

  // V^T bounce into LDS (pack node pairs)
#pragma unroll
  for (int mt = 0; mt < 2; ++mt)
#pragma unroll
    for (int nt = 0; nt < 4; ++nt)
#pragma unroll
      for (int r = 0; r < 4; r += 2) {
        int nl = mbase + mt * 16 + quad * 4 + r;
        int c  = nt * 16 + m;
        *(half2v*)&sm.big.vtb[c][nl] = pk2(acc[mt][nt][r], acc[mt][nt][r + 1]);
      }
  __syncthreads();

  // coalesced V^T -> global (64 rows x 64 dwords)
  const unsigned* vdw = (const unsigned*)sm.big.vtb;   // row stride 68 dwords
  unsigned* outdw = (unsigned*)VT_g;
  for (int it = 0; it < 16; ++it) {
    int idx = it * 256 + t;
    int c = idx >> 6, jd = idx & 63;
    outdw[(size_t)(bt * 64 + c) * 256 + qn * 64 + jd] = vdw[c * 68 + jd];
  }
}

// ======== kernel 2: masked softmax(P) @ V + LayerNorm + transpose ===========
// 1D grid, 1536 blocks: bt = bx % NBT (XCD-aligned with k1's VT writer),
// itile = bx / NBT (64 i-rows). V staged to LDS in bulk per j-quarter (deep
// MLP); masks read direct from global (L2-hot 256 KB, hoisted across unroll).
struct SmemK2 {
  union {
    _Float16 vt[64][128];        // 16384 B  swizzled V^T quarter
    float otile[64][66];         // 16896 B  epilogue overlay
  } u;                           // 16896 B
  union {
    struct { _Float16 F[2][512]; _Float16 P[2][512]; } f;                       // 4096 B
    struct { float rsum[4][64]; float rsq[4][64]; float mu[64]; float rs[64]; } l; // 2560 B
  } v;
};                                // 20992 B -> 7 blocks/CU (LDS)

__launch_bounds__(256, 6)
__global__ void k2_attn(const _Float16* __restrict__ VT_g,
                        const float* __restrict__ s_src_g, const float* __restrict__ s_dst_g,
                        const unsigned char* __restrict__ maskb,
                        const float* __restrict__ gamma, const float* __restrict__ beta,
                        float* __restrict__ out) {
  __shared__ SmemK2 sm;
  const int t     = threadIdx.x;
  const int bx    = blockIdx.x;
  const int bt    = bx % NBT;    // XCD = bt % 8
  const int itile = bx / NBT;
  const int i0    = itile * 64;
  const int b     = bt / TDIM, tt = bt % TDIM;
  const int lane  = t & 63, w = t >> 6;
  const int h = w >> 1, ihalf = w & 1;
  const int m = lane & 15, quad = lane >> 4;

  // stage F/Fp as f16 (1024 exp2 pairs per block)
  for (int it = 0; it < 4; ++it) {
    int idx = it * 256 + t;
    float d = s_dst_g[(size_t)bt * 2 * NDIM + idx];
    ((_Float16*)sm.v.f.F)[idx] = (_Float16)exp2_fast(d);
    ((_Float16*)sm.v.f.P)[idx] = (_Float16)exp2_fast(0.2f * d);
  }
  // per-row source factors as f16 splats (bias -6 keeps products f16-normal)
  half8v E8[2], Q8[2];
#pragma unroll
  for (int mt = 0; mt < 2; ++mt) {
    float sv = s_src_g[(size_t)(bt * 2 + h) * NDIM + i0 + ihalf * 32 + mt * 16 + m];
    _Float16 ev = (_Float16)exp2_fast(sv - 6.f);
    _Float16 qv = (_Float16)exp2_fast(0.2f * sv - 6.f);
#pragma unroll
    for (int jj = 0; jj < 8; ++jj) { E8[mt][jj] = ev; Q8[mt][jj] = qv; }
  }

  float4v acc[2][2], accs[2];
#pragma unroll
  for (int mt = 0; mt < 2; ++mt) {
#pragma unroll
    for (int r = 0; r < 4; ++r) { acc[mt][0][r] = 0.f; acc[mt][1][r] = 0.f; accs[mt][r] = 0.f; }
  }
  const half8v bones = {(_Float16)1.f, (_Float16)1.f, (_Float16)1.f, (_Float16)1.f,
                        (_Float16)1.f, (_Float16)1.f, (_Float16)1.f, (_Float16)1.f};

  const unsigned char* mrow0 = maskb + (size_t)(i0 + ihalf * 32 + m) * NDIM;
  const unsigned char* mrow1 = mrow0 + 16 * NDIM;
  const uint4* vsrc = (const uint4*)VT_g + (size_t)bt * 64 * 64;  // 64 rows x 64 uint4
  const int r0 = h * 32 + m;
  const int rsw = (r0 & 7) * 8;

  for (int js = 0; js < 4; ++js) {
    __syncthreads();   // previous quarter's vt fully consumed (also covers F/P stage)
    // bulk-stage V^T quarter with XOR swizzle (4 independent uint4 loads in flight)
#pragma unroll
    for (int it = 0; it < 4; ++it) {
      int idx = it * 256 + t;
      int c = idx >> 4, ch = idx & 15;
      uint4 val = vsrc[c * 64 + js * 16 + ch];
      *(uint4*)&sm.u.vt[c][(ch * 8) ^ ((c & 7) * 8)] = val;
    }
    __syncthreads();

#pragma unroll
    for (int ksl = 0; ksl < 4; ++ksl) {
      int jq = ksl * 32 + quad * 8;   // j within quarter
      int jo = js * 128 + jq;         // absolute j
      half8v F8 = *(const half8v*)&sm.v.f.F[h][jo];
      half8v P8 = *(const half8v*)&sm.v.f.P[h][jo];
      half8v b0 = *(const half8v*)&sm.u.vt[r0][jq ^ rsw];
      half8v b1 = *(const half8v*)&sm.u.vt[r0 + 16][jq ^ rsw];
      uint2 mv0 = *(const uint2*)(mrow0 + jo);
      uint2 mv1 = *(const uint2*)(mrow1 + jo);
#pragma unroll
      for (int mt = 0; mt < 2; ++mt) {
        uint2 mv = mt ? mv1 : mv0;
        half8v e8 = __builtin_elementwise_max(E8[mt] * F8, Q8[mt] * P8);  // pk_mul/pk_max
        uint4 eu = __builtin_bit_cast(uint4, e8);
        eu.x &= __builtin_amdgcn_perm(0u, mv.x, 0x01010000u);
        eu.y &= __builtin_amdgcn_perm(0u, mv.x, 0x03030202u);
        eu.z &= __builtin_amdgcn_perm(0u, mv.y, 0x01010000u);
        eu.w &= __builtin_amdgcn_perm(0u, mv.y, 0x03030202u);
        half8v af = __builtin_bit_cast(half8v, eu);
        acc[mt][0] = __builtin_amdgcn_mfma_f32_16x16x32_f16(af, b0,    acc[mt][0], 0, 0, 0);
        acc[mt][1] = __builtin_amdgcn_mfma_f32_16x16x32_f16(af, b1,    acc[mt][1], 0, 0, 0);
        accs[mt]   = __builtin_amdgcn_mfma_f32_16x16x32_f16(af, bones, accs[mt],   0, 0, 0);
      }
    }
  }

  __syncthreads();   // vt dead -> otile overlay
  // normalize by row sums (same C-layout row as acc -> no shuffle needed)
#pragma unroll
  for (int mt = 0; mt < 2; ++mt)
#pragma unroll
    for (int r = 0; r < 4; ++r) {
      float sc = __builtin_amdgcn_rcpf(accs[mt][r]);
      int i_loc = ihalf * 32 + mt * 16 + quad * 4 + r;
#pragma unroll
      for (int nt = 0; nt < 2; ++nt)
        sm.u.otile[i_loc][h * 32 + nt * 16 + m] = acc[mt][nt][r] * sc;
    }
  __syncthreads();   // also separates last F/P read from LN-stats overlay

  // LayerNorm over C=64 per row
  {
    int i = t & 63, cg = t >> 6;
    float s1 = 0.f, s2 = 0.f;
#pragma unroll
    for (int cc = 0; cc < 16; ++cc) {
      float v = sm.u.otile[i][cg * 16 + cc];
      s1 += v; s2 += v * v;
    }
    sm.v.l.rsum[cg][i] = s1;
    sm.v.l.rsq[cg][i]  = s2;
  }
  __syncthreads();
  if (t < 64) {
    int i = t;
    float s1 = 0.f, s2 = 0.f;
#pragma unroll
    for (int cg = 0; cg < 4; ++cg) { s1 += sm.v.l.rsum[cg][i]; s2 += sm.v.l.rsq[cg][i]; }
    float mu  = s1 * (1.f / 64.f);
    float var = s2 * (1.f / 64.f) - mu * mu;
    sm.v.l.mu[i] = mu;
    sm.v.l.rs[i] = rsqrtf(var + 1e-5f);
  }
  __syncthreads();
  {
    int i = t & 63, cg = t >> 6;
    float mu = sm.v.l.mu[i], rs = sm.v.l.rs[i];
    int n = i0 + i;
#pragma unroll
    for (int cc = 0; cc < 16; ++cc) {
      int c = cg * 16 + cc;
      float v = (sm.u.otile[i][c] - mu) * rs * gamma[c] + beta[c];
      out[((size_t)(b * CDIM + c) * TDIM + tt) * NDIM + n] = v;
    }
  }
}

// ---------------------------------------------------------------------------
extern "C" void kernel_launch(void* const* d_in, const int* in_sizes, int n_in,
                              void* d_out, int out_size, void* d_ws, size_t ws_size,
                              hipStream_t stream) {
  const float* x     = (const float*)d_in[0];
  const int*   gso   = (const int*)d_in[1];
  const float* Wq    = (const float*)d_in[2];
  const float* Wk    = (const float*)d_in[3];
  const float* Wv    = (const float*)d_in[4];
  const float* a_src = (const float*)d_in[5];
  const float* a_dst = (const float*)d_in[6];
  const float* gamma = (const float*)d_in[7];
  const float* beta  = (const float*)d_in[8];
  float* out = (float*)d_out;

  char* ws = (char*)d_ws;
  _Float16* VT_g  = (_Float16*)ws;
  float*    s_src = (float*)(ws + 12582912);
  float*    s_dst = (float*)(ws + 13369344);
  unsigned char* maskb = (unsigned char*)(ws + 14155776);

  k1_v<<<832, 256, 0, stream>>>(x, Wv, Wq, Wk, a_src, a_dst, gso,
                                VT_g, s_src, s_dst, maskb);
  k2_attn<<<1536, 256, 0, stream>>>(VT_g, s_src, s_dst, maskb, gamma, beta, out);
}